// Round 1
// baseline (207.472 us; speedup 1.0000x reference)
//
#include <hip/hip_runtime.h>
#include <math.h>

#define LEAK 0.01f

__device__ __forceinline__ float lrelu(float x) { return fmaxf(x, LEAK * x); }
__device__ __forceinline__ float fast_rcp(float x) { return __builtin_amdgcn_rcpf(x); }
__device__ __forceinline__ float sigmoid_f(float x) {
    // 1/(1+exp(-x)) = rcp(1+exp2(-x*log2e))
    return fast_rcp(1.0f + exp2f(-1.44269504f * x));
}
__device__ __forceinline__ float tanh_f(float x) {
    // tanh(x) = 2*sigmoid(2x)-1
    return 2.0f * fast_rcp(1.0f + exp2f(-2.88539008f * x)) - 1.0f;
}

#define L1C 508
#define L1P 170
#define L2C 166
#define L2P 56
#define L3C 52
#define L3P 18
#define TT 18

// ---------------------------------------------------------------------------
// K1: per-flow conv1d x3 (+lrelu, +maxpool3 fused; pool windows are disjoint)
// one block = one flow (b in [0,4096)), everything staged in LDS.
// ---------------------------------------------------------------------------
__global__ __launch_bounds__(256) void conv_kernel(
    const float* __restrict__ in,
    const float* __restrict__ W1, const float* __restrict__ b1,
    const float* __restrict__ W2, const float* __restrict__ b2,
    const float* __restrict__ W3, const float* __restrict__ b3,
    float* __restrict__ xseq)
{
    // guard-padded LDS: boundary taps read garbage but are masked out of max
    __shared__ __align__(16) float xsraw[24 + 1536 + 24];
    __shared__ __align__(16) float y1raw[16 + L1P * 10 + 32];
    __shared__ __align__(16) float y2raw[8 + L2P * 5 + 24];
    float* xs = xsraw + 24;   // xs[l*3+p] == input layout [L][P]
    float* y1 = y1raw + 16;   // y1[o*10+co]
    float* y2 = y2raw + 8;    // y2[o*5+co]

    const int tid = threadIdx.x;
    const int b = blockIdx.x;

    { // load input, 1536 floats, coalesced float4
        const float4* src = (const float4*)(in + (size_t)b * 1536);
        float4* dst4 = (float4*)xs;   // +24 floats = 96 B, 16B aligned
        for (int i = tid; i < 384; i += 256) dst4[i] = src[i];
    }
    __syncthreads();

    // ---- conv1 (3->10, k5, L=508) + lrelu + pool3 -> y1[170][10] ----
    {
        const int co = tid % 10;
        const int ob = tid / 10;            // 0..25
        float w[15];
        #pragma unroll
        for (int q = 0; q < 15; ++q) w[q] = W1[co * 15 + q];
        const float bias = b1[co];
        if (tid < 250) {
            for (int r = 0; r < 7; ++r) {
                int o = ob + 25 * r;
                if (o < L1P) {
                    int t0 = 3 * o - 1;
                    float a0 = bias, a1 = bias, a2 = bias;
                    #pragma unroll
                    for (int p = 0; p < 3; ++p) {
                        float yv[7];
                        #pragma unroll
                        for (int m = 0; m < 7; ++m) yv[m] = xs[3 * (t0 + m) + p];
                        #pragma unroll
                        for (int k = 0; k < 5; ++k) {
                            float wv = w[p * 5 + k];
                            a0 = fmaf(wv, yv[k], a0);
                            a1 = fmaf(wv, yv[k + 1], a1);
                            a2 = fmaf(wv, yv[k + 2], a2);
                        }
                    }
                    float best = -3.0e38f;
                    if (t0 >= 0)        best = fmaxf(best, lrelu(a0));
                    best = fmaxf(best, lrelu(a1));          // 3o always valid
                    if (t0 + 2 < L1C)   best = fmaxf(best, lrelu(a2));
                    y1[o * 10 + co] = best;
                }
            }
        }
    }
    __syncthreads();

    // ---- conv2 (10->5, k5, L=166) + lrelu + pool3 -> y2[56][5] ----
    {
        const int co = tid % 5;
        const int ob = tid / 5;             // 0..51
        float w[50];
        #pragma unroll
        for (int q = 0; q < 50; ++q) w[q] = W2[co * 50 + q];
        const float bias = b2[co];
        if (tid < 255) {
            for (int r = 0; r < 2; ++r) {
                int o = ob + 51 * r;
                if (o < L2P) {
                    int t0 = 3 * o - 1;
                    float a0 = bias, a1 = bias, a2 = bias;
                    #pragma unroll
                    for (int ci = 0; ci < 10; ++ci) {
                        float yv[7];
                        #pragma unroll
                        for (int m = 0; m < 7; ++m) yv[m] = y1[(t0 + m) * 10 + ci];
                        #pragma unroll
                        for (int k = 0; k < 5; ++k) {
                            float wv = w[ci * 5 + k];
                            a0 = fmaf(wv, yv[k], a0);
                            a1 = fmaf(wv, yv[k + 1], a1);
                            a2 = fmaf(wv, yv[k + 2], a2);
                        }
                    }
                    float best = -3.0e38f;
                    if (t0 >= 0)        best = fmaxf(best, lrelu(a0));
                    best = fmaxf(best, lrelu(a1));
                    if (t0 + 2 < L2C)   best = fmaxf(best, lrelu(a2));
                    y2[o * 5 + co] = best;
                }
            }
        }
    }
    __syncthreads();

    // ---- conv3 (5->10, k5, L=52) + lrelu + pool3 -> xseq[b][t=o][j=co] ----
    {
        const int co = tid % 10;
        const int o = tid / 10;             // 0..25
        if (o < L3P) {
            float w[25];
            #pragma unroll
            for (int q = 0; q < 25; ++q) w[q] = W3[co * 25 + q];
            const float bias = b3[co];
            int t0 = 3 * o - 1;
            float a0 = bias, a1 = bias, a2 = bias;
            #pragma unroll
            for (int ci = 0; ci < 5; ++ci) {
                float yv[7];
                #pragma unroll
                for (int m = 0; m < 7; ++m) yv[m] = y2[(t0 + m) * 5 + ci];
                #pragma unroll
                for (int k = 0; k < 5; ++k) {
                    float wv = w[ci * 5 + k];
                    a0 = fmaf(wv, yv[k], a0);
                    a1 = fmaf(wv, yv[k + 1], a1);
                    a2 = fmaf(wv, yv[k + 2], a2);
                }
            }
            float best = -3.0e38f;
            if (t0 >= 0)        best = fmaxf(best, lrelu(a0));
            best = fmaxf(best, lrelu(a1));
            if (t0 + 2 < L3C)   best = fmaxf(best, lrelu(a2));
            xseq[(size_t)b * 180 + o * 10 + co] = best;
        }
    }
}

// ---------------------------------------------------------------------------
// K2: flow LSTM (3 layers, T=18, H=10) over 4096 flows.
// 16 lanes per flow (4 flows per wave); lane j<10 owns hidden unit j and
// computes all 4 of its gates from register-resident weights. h is exchanged
// through LDS strictly within the owning wave (same-wave DS ordering).
// ---------------------------------------------------------------------------
__global__ __launch_bounds__(256) void flow_lstm_kernel(
    const float* __restrict__ xseq,
    const float* __restrict__ fWih, const float* __restrict__ fWhh,
    const float* __restrict__ fb,
    float* __restrict__ fv)
{
    __shared__ __align__(16) float sbuf[3][16 * 18 * 10];
    const int tid = threadIdx.x;
    const int blk = blockIdx.x;

    { // stage this block's 16 flows: [e][t][j], contiguous 2880 floats
        const float* src = xseq + (size_t)blk * 2880;
        for (int i = tid; i < 2880; i += 256) sbuf[0][i] = src[i];
    }
    __syncthreads();

    const int el = tid >> 4;                 // local flow 0..15 (wave-private 4)
    const int j = tid & 15;
    const int jj = (j < 10) ? j : 0;
    const int base = el * 180;

    float fv_acc = 0.0f;

    for (int l = 0; l < 3; ++l) {
        const float* Wi = fWih + l * 400;
        const float* Wh = fWhh + l * 400;
        const float* bb = fb + l * 40;
        float wi0[10], wi1[10], wi2[10], wi3[10];
        float wh0[10], wh1[10], wh2[10], wh3[10];
        #pragma unroll
        for (int k = 0; k < 10; ++k) {
            wi0[k] = Wi[jj * 10 + k];
            wi1[k] = Wi[(10 + jj) * 10 + k];
            wi2[k] = Wi[(20 + jj) * 10 + k];
            wi3[k] = Wi[(30 + jj) * 10 + k];
            wh0[k] = Wh[jj * 10 + k];
            wh1[k] = Wh[(10 + jj) * 10 + k];
            wh2[k] = Wh[(20 + jj) * 10 + k];
            wh3[k] = Wh[(30 + jj) * 10 + k];
        }
        const float bi = bb[jj], bf = bb[10 + jj], bg = bb[20 + jj], bo = bb[30 + jj];

        const float* inb = sbuf[l];
        float* outb = sbuf[(l + 1) % 3];
        float c = 0.0f;
        float hj = 0.0f;

        for (int t = 0; t < TT; ++t) {
            float x[10], h[10];
            const float* xp = inb + base + t * 10;
            #pragma unroll
            for (int k = 0; k < 5; ++k) {
                float2 v = ((const float2*)xp)[k];
                x[2 * k] = v.x; x[2 * k + 1] = v.y;
            }
            if (t > 0) {
                const float* hp = outb + base + (t - 1) * 10;
                #pragma unroll
                for (int k = 0; k < 5; ++k) {
                    float2 v = ((const float2*)hp)[k];
                    h[2 * k] = v.x; h[2 * k + 1] = v.y;
                }
            } else {
                #pragma unroll
                for (int k = 0; k < 10; ++k) h[k] = 0.0f;
            }
            float gi = bi, gf = bf, gg = bg, go = bo;
            #pragma unroll
            for (int k = 0; k < 10; ++k) {
                gi = fmaf(wi0[k], x[k], gi); gi = fmaf(wh0[k], h[k], gi);
                gf = fmaf(wi1[k], x[k], gf); gf = fmaf(wh1[k], h[k], gf);
                gg = fmaf(wi2[k], x[k], gg); gg = fmaf(wh2[k], h[k], gg);
                go = fmaf(wi3[k], x[k], go); go = fmaf(wh3[k], h[k], go);
            }
            const float ai = sigmoid_f(gi), af = sigmoid_f(gf);
            const float ag = tanh_f(gg),    ao = sigmoid_f(go);
            c = af * c + ai * ag;
            hj = ao * tanh_f(c);
            if (j < 10) outb[base + t * 10 + j] = hj;
            __asm__ __volatile__("" ::: "memory");   // keep DS order; HW is in-order per wave
        }
        if (l >= 1) fv_acc += hj;   // h_n of layers 1 and 2 at t=17
    }
    if (j < 10) fv[(size_t)(blk * 16 + el) * 10 + j] = fv_acc;
}

// ---------------------------------------------------------------------------
// K3: trace LSTM (3 layers, T=64, H=10) for 64 rows + fused per-row MLP.
// One wave per row. 40 gate-lanes; cross-lane via __shfl only (no barriers).
// The 3 layers are software-pipelined in-register: per tick compute
// layer2@t-2, layer1@t-1, layer0@t so their dependency chains overlap.
// ---------------------------------------------------------------------------
__global__ __launch_bounds__(64) void trace_mlp_kernel(
    const float* __restrict__ fv,
    const float* __restrict__ tWih, const float* __restrict__ tWhh,
    const float* __restrict__ tb,
    const float* __restrict__ L1W, const float* __restrict__ L1b,
    const float* __restrict__ L2W, const float* __restrict__ L2b,
    const float* __restrict__ L3W, const float* __restrict__ L3b,
    const float* __restrict__ L4W, const float* __restrict__ L4b,
    float* __restrict__ out)
{
    __shared__ __align__(16) float xrow[640];
    __shared__ __align__(16) float m1[128];
    __shared__ __align__(16) float m2b[256];
    __shared__ __align__(16) float m3[64];

    const int lane = threadIdx.x;
    const int ti = blockIdx.x;

    for (int i = lane; i < 640; i += 64) xrow[i] = fv[(size_t)ti * 640 + i];
    __asm__ __volatile__("" ::: "memory");   // same-wave DS ordering

    const int gt = lane / 10;                 // 0:i 1:f 2:g 3:o (lanes<40)
    const bool isg = (gt == 2);
    const float m2g = isg ? 2.0f : 1.0f;      // tanh(x)=2*sig(2x)-1
    const float am = isg ? 2.0f : 1.0f;
    const float ab = isg ? -1.0f : 0.0f;

    const int r = (lane < 40) ? lane : 0;     // gate row
    float wi0[10], wh0[10], wi1[10], wh1[10], wi2[10], wh2[10];
    #pragma unroll
    for (int k = 0; k < 10; ++k) {
        wi0[k] = tWih[r * 10 + k];
        wh0[k] = tWhh[r * 10 + k];
        wi1[k] = tWih[400 + r * 10 + k];
        wh1[k] = tWhh[400 + r * 10 + k];
        wi2[k] = tWih[800 + r * 10 + k];
        wh2[k] = tWhh[800 + r * 10 + k];
    }
    const float bs0 = tb[r], bs1 = tb[40 + r], bs2 = tb[80 + r];

    float hb0[10], hb1[10], hb2[10];
    #pragma unroll
    for (int k = 0; k < 10; ++k) { hb0[k] = 0.0f; hb1[k] = 0.0f; hb2[k] = 0.0f; }
    float c0 = 0.0f, c1 = 0.0f, c2 = 0.0f;

    for (int tick = 0; tick < 66; ++tick) {
        float xn[10];
        if (tick < 64) {                       // prefetch x(t=tick); consumed after L2/L1
            const float* xp = xrow + tick * 10;
            #pragma unroll
            for (int k = 0; k < 5; ++k) {
                float2 v = ((const float2*)xp)[k];
                xn[2 * k] = v.x; xn[2 * k + 1] = v.y;
            }
        }
        if (tick >= 2) {                       // layer2 @ t-2, input = hb1 (prev tick)
            float g = bs2;
            #pragma unroll
            for (int k = 0; k < 10; ++k) {
                g = fmaf(wi2[k], hb1[k], g);
                g = fmaf(wh2[k], hb2[k], g);
            }
            float a = am * sigmoid_f(m2g * g) + ab;
            float af = __shfl(a, lane + 10);
            float ag = __shfl(a, lane + 20);
            float ao = __shfl(a, lane + 30);
            c2 = af * c2 + a * ag;             // a == a_i in lanes 0..9
            float h = ao * tanh_f(c2);
            #pragma unroll
            for (int k = 0; k < 10; ++k) hb2[k] = __shfl(h, k);
        }
        if (tick >= 1 && tick < 65) {          // layer1 @ t-1, input = hb0 (prev tick)
            float g = bs1;
            #pragma unroll
            for (int k = 0; k < 10; ++k) {
                g = fmaf(wi1[k], hb0[k], g);
                g = fmaf(wh1[k], hb1[k], g);
            }
            float a = am * sigmoid_f(m2g * g) + ab;
            float af = __shfl(a, lane + 10);
            float ag = __shfl(a, lane + 20);
            float ao = __shfl(a, lane + 30);
            c1 = af * c1 + a * ag;
            float h = ao * tanh_f(c1);
            #pragma unroll
            for (int k = 0; k < 10; ++k) hb1[k] = __shfl(h, k);
        }
        if (tick < 64) {                       // layer0 @ t
            float g = bs0;
            #pragma unroll
            for (int k = 0; k < 10; ++k) {
                g = fmaf(wi0[k], xn[k], g);
                g = fmaf(wh0[k], hb0[k], g);
            }
            float a = am * sigmoid_f(m2g * g) + ab;
            float af = __shfl(a, lane + 10);
            float ag = __shfl(a, lane + 20);
            float ao = __shfl(a, lane + 30);
            c0 = af * c0 + a * ag;
            float h = ao * tanh_f(c0);
            #pragma unroll
            for (int k = 0; k < 10; ++k) hb0[k] = __shfl(h, k);
        }
    }

    // tv = h_n(layer2) + h_n(layer1)
    float tv[10];
    #pragma unroll
    for (int k = 0; k < 10; ++k) tv[k] = hb1[k] + hb2[k];

    // ---- fused per-row MLP: 10 ->128 ->256 ->64 ->7 ----
    {
        float a0 = L1b[lane], a1 = L1b[lane + 64];
        #pragma unroll
        for (int k = 0; k < 10; ++k) {
            a0 = fmaf(L1W[lane * 10 + k], tv[k], a0);
            a1 = fmaf(L1W[(lane + 64) * 10 + k], tv[k], a1);
        }
        m1[lane] = lrelu(a0);
        m1[lane + 64] = lrelu(a1);
    }
    __asm__ __volatile__("" ::: "memory");
    {
        float acc[4];
        #pragma unroll
        for (int q = 0; q < 4; ++q) acc[q] = L2b[lane + 64 * q];
        for (int k = 0; k < 128; ++k) {
            float hv = m1[k];
            #pragma unroll
            for (int q = 0; q < 4; ++q)
                acc[q] = fmaf(L2W[(size_t)(lane + 64 * q) * 128 + k], hv, acc[q]);
        }
        #pragma unroll
        for (int q = 0; q < 4; ++q) m2b[lane + 64 * q] = lrelu(acc[q]);
    }
    __asm__ __volatile__("" ::: "memory");
    {
        float acc = L3b[lane];
        for (int k = 0; k < 256; ++k)
            acc = fmaf(L3W[(size_t)lane * 256 + k], m2b[k], acc);
        m3[lane] = lrelu(acc);
    }
    __asm__ __volatile__("" ::: "memory");
    if (lane < 7) {
        float acc = L4b[lane];
        #pragma unroll
        for (int k = 0; k < 64; ++k)
            acc = fmaf(L4W[lane * 64 + k], m3[k], acc);
        out[ti * 7 + lane] = acc;
    }
}

// ---------------------------------------------------------------------------
extern "C" void kernel_launch(void* const* d_in, const int* in_sizes, int n_in,
                              void* d_out, int out_size, void* d_ws, size_t ws_size,
                              hipStream_t stream)
{
    const float* data_in = (const float*)d_in[0];
    const float* W1 = (const float*)d_in[1];
    const float* b1 = (const float*)d_in[2];
    const float* W2 = (const float*)d_in[3];
    const float* b2 = (const float*)d_in[4];
    const float* W3 = (const float*)d_in[5];
    const float* b3 = (const float*)d_in[6];
    const float* fWih = (const float*)d_in[7];
    const float* fWhh = (const float*)d_in[8];
    const float* fb = (const float*)d_in[9];
    const float* tWih = (const float*)d_in[10];
    const float* tWhh = (const float*)d_in[11];
    const float* tb = (const float*)d_in[12];
    const float* L1W = (const float*)d_in[13];
    const float* L1b = (const float*)d_in[14];
    const float* L2W = (const float*)d_in[15];
    const float* L2b = (const float*)d_in[16];
    const float* L3W = (const float*)d_in[17];
    const float* L3b = (const float*)d_in[18];
    const float* L4W = (const float*)d_in[19];
    const float* L4b = (const float*)d_in[20];

    float* xseq = (float*)d_ws;            // 4096*180 floats
    float* fv = xseq + 4096 * 180;         // 4096*10 floats
    float* outp = (float*)d_out;           // 64*7 floats

    conv_kernel<<<4096, 256, 0, stream>>>(data_in, W1, b1, W2, b2, W3, b3, xseq);
    flow_lstm_kernel<<<256, 256, 0, stream>>>(xseq, fWih, fWhh, fb, fv);
    trace_mlp_kernel<<<64, 64, 0, stream>>>(fv, tWih, tWhh, tb,
                                            L1W, L1b, L2W, L2b, L3W, L3b,
                                            L4W, L4b, outp);
}